// Round 8
// baseline (521.310 us; speedup 1.0000x reference)
//
#include <hip/hip_runtime.h>

typedef unsigned short u16;
typedef unsigned int u32;

#define S 2048
#define HID 2048
#define NH 16
#define NKV 4
#define D 128
#define QKVP 3072  // QKV buffer pitch (Q|K|V concat per row)
#define SCALE 0.08838834764831845f  // 1/sqrt(128)
#define NEG_INF -3.0e38f

typedef __attribute__((ext_vector_type(8))) short short8;  // 8 bf16 = 4 VGPRs
typedef __attribute__((ext_vector_type(4))) float f32x4;

__device__ __forceinline__ float bf2f(u16 u) {
  union { u32 i; float f; } c; c.i = ((u32)u) << 16; return c.f;
}
__device__ __forceinline__ u16 f2bf(float f) {
  union { float f; u32 i; } c; c.f = f;
  u32 x = c.i;
  u32 r = x + 0x7fffu + ((x >> 16) & 1u);  // RNE
  return (u16)(r >> 16);
}

// ---------------- fused prep: cvt(hidden) + transpose Wq/Wk/Wv/Wo -----------
__device__ __forceinline__ void transpose_body(const float* __restrict__ src,
                                               u16* __restrict__ dst,
                                               int N, int K, int nt, int kt,
                                               int t, float (*T)[65]) {
#pragma unroll
  for (int it = 0; it < 4; ++it) {
    int r = it * 16 + (t >> 4), c = (t & 15) * 4;
    float4 v = *(const float4*)(src + (size_t)(kt + r) * N + nt + c);
    T[r][c] = v.x; T[r][c + 1] = v.y; T[r][c + 2] = v.z; T[r][c + 3] = v.w;
  }
  __syncthreads();
#pragma unroll
  for (int it = 0; it < 2; ++it) {
    int n = it * 32 + (t >> 3), k8 = (t & 7) * 8;
    ushort4 w0, w1;
    w0.x = f2bf(T[k8 + 0][n]); w0.y = f2bf(T[k8 + 1][n]);
    w0.z = f2bf(T[k8 + 2][n]); w0.w = f2bf(T[k8 + 3][n]);
    w1.x = f2bf(T[k8 + 4][n]); w1.y = f2bf(T[k8 + 5][n]);
    w1.z = f2bf(T[k8 + 6][n]); w1.w = f2bf(T[k8 + 7][n]);
    *(ushort4*)(dst + (size_t)(nt + n) * K + kt + k8) = w0;
    *(ushort4*)(dst + (size_t)(nt + n) * K + kt + k8 + 4) = w1;
  }
}

__global__ __launch_bounds__(256) void k_prep(const float* __restrict__ hidden,
                                              const float* __restrict__ Wq,
                                              const float* __restrict__ Wk,
                                              const float* __restrict__ Wv,
                                              const float* __restrict__ Wo,
                                              u16* __restrict__ Hb,
                                              u16* __restrict__ WT,
                                              u16* __restrict__ WoT) {
  __shared__ float T[64][65];
  const int b = blockIdx.x, t = threadIdx.x;
  if (b < 2048) {  // cvt hidden -> bf16
    int i = (b * 256 + t) * 8;
    float4 v0 = *(const float4*)(hidden + i);
    float4 v1 = *(const float4*)(hidden + i + 4);
    ushort4 w0, w1;
    w0.x = f2bf(v0.x); w0.y = f2bf(v0.y); w0.z = f2bf(v0.z); w0.w = f2bf(v0.w);
    w1.x = f2bf(v1.x); w1.y = f2bf(v1.y); w1.z = f2bf(v1.z); w1.w = f2bf(v1.w);
    *(ushort4*)(Hb + i) = w0;
    *(ushort4*)(Hb + i + 4) = w1;
  } else if (b < 2048 + 1536) {  // Wq|Wk|Wv transpose
    int bb = b - 2048, bx = bb % 48, by = bb / 48;
    const float* src; u16* dst; int N, nt;
    if (bx < 32)      { src = Wq; dst = WT;                  N = 2048; nt = bx * 64; }
    else if (bx < 40) { src = Wk; dst = WT + 2048ull * 2048; N = 512;  nt = (bx - 32) * 64; }
    else              { src = Wv; dst = WT + 2560ull * 2048; N = 512;  nt = (bx - 40) * 64; }
    transpose_body(src, dst, N, 2048, nt, by * 64, t, T);
  } else {  // Wo transpose
    int bb = b - 3584, bx = bb % 32, by = bb / 32;
    transpose_body(Wo, WoT, 2048, 2048, bx * 64, by * 64, t, T);
  }
}

// ------- V transpose: QKV V-section [s][2560+gd] bf16 -> Vt[gd][s] bf16 -----
__global__ __launch_bounds__(256) void k_vt(const u16* __restrict__ QKV,
                                            u16* __restrict__ Vt) {
  __shared__ u16 T[64][66];
  const int t = threadIdx.x;
  const int s0 = blockIdx.x * 64, d0 = blockIdx.y * 64;
#pragma unroll
  for (int it = 0; it < 4; ++it) {
    int r = it * 16 + (t >> 4), c = (t & 15) * 4;
    ushort4 v = *(const ushort4*)(QKV + (size_t)(s0 + r) * QKVP + 2560 + d0 + c);
    T[r][c] = v.x; T[r][c + 1] = v.y; T[r][c + 2] = v.z; T[r][c + 3] = v.w;
  }
  __syncthreads();
#pragma unroll
  for (int it = 0; it < 4; ++it) {
    int dd = it * 16 + (t >> 4), sc = (t & 15) * 4;
    ushort4 w;
    w.x = T[sc + 0][dd]; w.y = T[sc + 1][dd];
    w.z = T[sc + 2][dd]; w.w = T[sc + 3][dd];
    *(ushort4*)(Vt + (size_t)(d0 + dd) * S + s0 + sc) = w;
  }
}

// ---------------- MFMA GEMM v5: L2-direct fragments, no LDS, no barriers ----
// C[M,N] = A[M,K] * BT[N,K]^T. Each b128 frag load = 16 rows x 64B contiguous
// = 16 cache lines; A/B tiles are L2-resident across the grid's re-reads.
__global__ __launch_bounds__(256) void k_gemm_mfma(const u16* __restrict__ A,
                                                   const u16* __restrict__ BT,
                                                   void* __restrict__ Cout,
                                                   int N, int K, int out_bf16) {
  const int t = threadIdx.x, w = t >> 6, lane = t & 63;
  const int l15 = lane & 15, quad = lane >> 4;
  const int m0 = blockIdx.y * 128, n0 = blockIdx.x * 128;
  const int wr = w >> 1, wc = w & 1;

  const u16* Ab = A + (size_t)(m0 + wr * 64 + l15) * K + quad * 8;
  const u16* Bb = BT + (size_t)(n0 + wc * 64 + l15) * K + quad * 8;
  const size_t r16 = (size_t)16 * K;

  f32x4 acc[4][4];
#pragma unroll
  for (int i = 0; i < 4; ++i)
#pragma unroll
    for (int j = 0; j < 4; ++j) acc[i][j] = (f32x4){0.f, 0.f, 0.f, 0.f};

#pragma unroll 2
  for (int k0 = 0; k0 < K; k0 += 32) {
    short8 af[4], bf[4];
#pragma unroll
    for (int i = 0; i < 4; ++i) af[i] = *(const short8*)(Ab + i * r16 + k0);
#pragma unroll
    for (int j = 0; j < 4; ++j) bf[j] = *(const short8*)(Bb + j * r16 + k0);
#pragma unroll
    for (int i = 0; i < 4; ++i)
#pragma unroll
      for (int j = 0; j < 4; ++j)
        acc[i][j] = __builtin_amdgcn_mfma_f32_16x16x32_bf16(af[i], bf[j], acc[i][j], 0, 0, 0);
  }

  if (out_bf16) {
    u16* C = (u16*)Cout;
#pragma unroll
    for (int i = 0; i < 4; ++i)
#pragma unroll
      for (int j = 0; j < 4; ++j) {
        int col = n0 + wc * 64 + j * 16 + l15;
#pragma unroll
        for (int r = 0; r < 4; ++r)
          C[(size_t)(m0 + wr * 64 + i * 16 + quad * 4 + r) * N + col] = f2bf(acc[i][j][r]);
      }
  } else {
    float* C = (float*)Cout;
#pragma unroll
    for (int i = 0; i < 4; ++i)
#pragma unroll
      for (int j = 0; j < 4; ++j) {
        int col = n0 + wc * 64 + j * 16 + l15;
#pragma unroll
        for (int r = 0; r < 4; ++r)
          C[(size_t)(m0 + wr * 64 + i * 16 + quad * 4 + r) * N + col] = acc[i][j][r];
      }
  }
}

// ------------- per-(s,head) RMSNorm + RoPE, Q and K in one launch -----------
__global__ __launch_bounds__(128) void k_norm_rope(u16* __restrict__ QKV,
                                                   const float* __restrict__ qsc,
                                                   const float* __restrict__ ksc,
                                                   const float* __restrict__ cosp,
                                                   const float* __restrict__ sinp) {
  const int s = blockIdx.x, hh = blockIdx.y, d = threadIdx.x;
  u16* row; const float* sc; float scale;
  if (hh < NH) { row = QKV + (size_t)s * QKVP + hh * D;            sc = qsc; scale = SCALE; }
  else         { row = QKV + (size_t)s * QKVP + 2048 + (hh - NH) * D; sc = ksc; scale = 1.0f; }
  float x = bf2f(row[d]);
  float v = x * x;
#pragma unroll
  for (int o = 32; o; o >>= 1) v += __shfl_xor(v, o, 64);
  __shared__ float red[2];
  if ((d & 63) == 0) red[d >> 6] = v;
  __syncthreads();
  float var = (red[0] + red[1]) * (1.0f / 128.0f);
  float rinv = rsqrtf(var + 1e-6f) * scale;
  float xn = x * rinv * sc[d];
  __shared__ float sh[D];
  sh[d] = xn;
  __syncthreads();
  float rot = (d < 64) ? -sh[d + 64] : sh[d - 64];
  row[d] = f2bf(xn * cosp[s * D + d] + rot * sinp[s * D + d]);
}

// ---------------- flash attention v5: L2-direct K/V, barrier-free -----------
// Block: 256 thr (4 waves) = 64-row q-tile of one head; waves independent.
// K and V^T fragments are loaded straight from global (L2-resident: K+Vt
// = 4 MB total). Only P round-trips through per-wave LDS (no sync needed:
// same-wave ds ordering). No __syncthreads in the kernel at all.
#define PTP 72   // P pitch (u16)

__global__ __launch_bounds__(256) void k_flash(const u16* __restrict__ QKV,
                                               const u16* __restrict__ Vt,
                                               u16* __restrict__ O) {
  const int qt = 31 - (int)blockIdx.y;  // heaviest blocks of ALL heads first
  const int h = blockIdx.x, g = h >> 2;
  const int t = threadIdx.x;
  const int w = t >> 6, lane = t & 63, l15 = lane & 15, quad = lane >> 4;

  __shared__ __align__(16) u16 Pt[4][16 * PTP];  // 9 KB

  const int qbase = qt * 64 + w * 16;
  const int qrow = qbase + l15;

  short8 qf[4];
  {
    const u16* qp = QKV + (size_t)qrow * QKVP + h * D + quad * 8;
#pragma unroll
    for (int c = 0; c < 4; ++c) qf[c] = *(const short8*)(qp + c * 32);
  }

  // K fragment base: row (j + l15) of K-section, chunk c*32 + quad*8
  const u16* Kb = QKV + (size_t)l15 * QKVP + 2048 + g * D + quad * 8;
  // V^T fragment base: row (nc*16 + l15) of Vt, col j + kc*32 + quad*8
  const u16* Vb = Vt + (size_t)(g * D + l15) * S + quad * 8;

  float m = NEG_INF, l = 0.f;
  f32x4 oacc[8];
#pragma unroll
  for (int nc = 0; nc < 8; ++nc) oacc[nc] = (f32x4){0.f, 0.f, 0.f, 0.f};

  const int nt = qt + 1;
  for (int jt = 0; jt < nt; ++jt) {
    const int j0 = jt * 64;

    // ---- S^T = K x Q^T : row = key, col = q-row (l15); K frags from L2 ----
    f32x4 sa[4];
#pragma unroll
    for (int sub = 0; sub < 4; ++sub) {
      f32x4 acc = {0.f, 0.f, 0.f, 0.f};
#pragma unroll
      for (int c = 0; c < 4; ++c) {
        short8 kf = *(const short8*)(Kb + (size_t)(j0 + sub * 16) * QKVP + c * 32);
        acc = __builtin_amdgcn_mfma_f32_16x16x32_bf16(kf, qf[c], acc, 0, 0, 0);
      }
      sa[sub] = acc;
    }
    if (jt == nt - 1) {  // causal mask, diagonal tile only
#pragma unroll
      for (int sub = 0; sub < 4; ++sub) {
        int keyb = j0 + sub * 16 + quad * 4;
#pragma unroll
        for (int r = 0; r < 4; ++r)
          if (keyb + r > qrow) sa[sub][r] = NEG_INF;
      }
    }
    // ---- online softmax (per-lane state, 2 cross-quad shfl per reduce) ----
    float tmax = sa[0][0];
#pragma unroll
    for (int sub = 0; sub < 4; ++sub)
#pragma unroll
      for (int r = 0; r < 4; ++r) tmax = fmaxf(tmax, sa[sub][r]);
    tmax = fmaxf(tmax, __shfl_xor(tmax, 16, 64));
    tmax = fmaxf(tmax, __shfl_xor(tmax, 32, 64));
    float mn = fmaxf(m, tmax);
    float alpha = __expf(m - mn);
    m = mn;
    float rs = 0.f;
#pragma unroll
    for (int sub = 0; sub < 4; ++sub) {
      float p0 = __expf(sa[sub][0] - m);
      float p1 = __expf(sa[sub][1] - m);
      float p2 = __expf(sa[sub][2] - m);
      float p3 = __expf(sa[sub][3] - m);
      rs += (p0 + p1) + (p2 + p3);
      u32 lo = (u32)f2bf(p0) | ((u32)f2bf(p1) << 16);
      u32 hi = (u32)f2bf(p2) | ((u32)f2bf(p3) << 16);
      *(uint2*)&Pt[w][l15 * PTP + sub * 16 + quad * 4] = make_uint2(lo, hi);
    }
    rs += __shfl_xor(rs, 16, 64);
    rs += __shfl_xor(rs, 32, 64);
    l = l * alpha + rs;
#pragma unroll
    for (int nc = 0; nc < 8; ++nc) {
      oacc[nc][0] *= alpha; oacc[nc][1] *= alpha;
      oacc[nc][2] *= alpha; oacc[nc][3] *= alpha;
    }
    // ---- O^T += V^T x P^T : V frags from L2, P from per-wave LDS ----
#pragma unroll
    for (int kc = 0; kc < 2; ++kc) {
      short8 pf = *(const short8*)&Pt[w][l15 * PTP + kc * 32 + quad * 8];
#pragma unroll
      for (int nc = 0; nc < 8; ++nc) {
        short8 vf = *(const short8*)(Vb + (size_t)(nc * 16) * S + j0 + kc * 32);
        oacc[nc] = __builtin_amdgcn_mfma_f32_16x16x32_bf16(vf, pf, oacc[nc], 0, 0, 0);
      }
    }
  }

  // ---- epilogue: O[q][d] = O^T / l ----
  float inv = 1.0f / l;
  u16* orow = O + (size_t)qrow * HID + h * D;
#pragma unroll
  for (int nc = 0; nc < 8; ++nc) {
    ushort4 wv;
    wv.x = f2bf(oacc[nc][0] * inv); wv.y = f2bf(oacc[nc][1] * inv);
    wv.z = f2bf(oacc[nc][2] * inv); wv.w = f2bf(oacc[nc][3] * inv);
    *(ushort4*)(orow + nc * 16 + quad * 4) = wv;
  }
}

// ---------------- final RMSNorm over HIDDEN=2048 ----------------------------
__device__ __forceinline__ float blockSum256(float v, float* red, int t) {
#pragma unroll
  for (int o = 32; o; o >>= 1) v += __shfl_xor(v, o, 64);
  if ((t & 63) == 0) red[t >> 6] = v;
  __syncthreads();
  v = red[0] + red[1] + red[2] + red[3];
  __syncthreads();
  return v;
}

__global__ __launch_bounds__(256) void k_fnorm(const float* __restrict__ X,
                                               const float* __restrict__ sc,
                                               float* __restrict__ out) {
  const int s = blockIdx.x, t = threadIdx.x;
  const float* row = X + (size_t)s * HID;
  float4 r0 = *(const float4*)(row + t * 8);
  float4 r1 = *(const float4*)(row + t * 8 + 4);
  float x[8] = {r0.x, r0.y, r0.z, r0.w, r1.x, r1.y, r1.z, r1.w};
  float ss = 0.f;
#pragma unroll
  for (int ii = 0; ii < 8; ++ii) ss += x[ii] * x[ii];
  __shared__ float red[4];
  float tot = blockSum256(ss, red, t);
  float rinv = rsqrtf(tot * (1.0f / 2048.0f) + 1e-6f);
  float4 s0 = *(const float4*)(sc + t * 8);
  float4 s1 = *(const float4*)(sc + t * 8 + 4);
  float4 w0 = make_float4(x[0] * rinv * s0.x, x[1] * rinv * s0.y,
                          x[2] * rinv * s0.z, x[3] * rinv * s0.w);
  float4 w1 = make_float4(x[4] * rinv * s1.x, x[5] * rinv * s1.y,
                          x[6] * rinv * s1.z, x[7] * rinv * s1.w);
  *(float4*)(out + (size_t)s * HID + t * 8) = w0;
  *(float4*)(out + (size_t)s * HID + t * 8 + 4) = w1;
}

extern "C" void kernel_launch(void* const* d_in, const int* in_sizes, int n_in,
                              void* d_out, int out_size, void* d_ws, size_t ws_size,
                              hipStream_t stream) {
  const float* hidden = (const float*)d_in[0];
  const float* cosp   = (const float*)d_in[1];
  const float* sinp   = (const float*)d_in[2];
  const float* Wq     = (const float*)d_in[3];
  const float* Wk     = (const float*)d_in[4];
  const float* Wv     = (const float*)d_in[5];
  const float* Wo     = (const float*)d_in[6];
  const float* qsc    = (const float*)d_in[7];
  const float* ksc    = (const float*)d_in[8];
  const float* lsc    = (const float*)d_in[9];
  float* out = (float*)d_out;

  char* ws = (char*)d_ws;
  u16*   Hb  = (u16*)(ws);                   // [S][HID] bf16, 8 MiB
  u16*   WT  = (u16*)(ws + (8ull << 20));    // [3072][2048] bf16, 12 MiB
  u16*   An  = (u16*)(ws + (8ull << 20));    // overlays WT (after QKV GEMM)
  u16*   QKV = (u16*)(ws + (20ull << 20));   // [S][3072] bf16, 12 MiB
  float* Ob  = (float*)(ws + (20ull << 20)); // overlays QKV (after flash)
  u16*   Vtb = (u16*)(ws + (32ull << 20));   // [512][2048] bf16, 2 MiB
  u16*   WoT = (u16*)(ws + (34ull << 20));   // [2048][2048] bf16, 8 MiB

  k_prep<<<4608, 256, 0, stream>>>(hidden, Wq, Wk, Wv, Wo, Hb, WT, WoT);
  k_gemm_mfma<<<dim3(24, 16), 256, 0, stream>>>(Hb, WT, QKV, QKVP, 2048, 1);
  k_norm_rope<<<dim3(S, NH + NKV), 128, 0, stream>>>(QKV, qsc, ksc, cosp, sinp);
  k_vt<<<dim3(32, 8), 256, 0, stream>>>(QKV, Vtb);
  k_flash<<<dim3(NH, 32), 256, 0, stream>>>(QKV, Vtb, An);
  k_gemm_mfma<<<dim3(16, 16), 256, 0, stream>>>(An, WoT, Ob, 2048, 2048, 0);
  k_fnorm<<<S, 256, 0, stream>>>(Ob, lsc, out);
}